// Round 3
// baseline (4477.629 us; speedup 1.0000x reference)
//
#include <hip/hip_runtime.h>
#include <math.h>

#define NH   4096
#define KCAT 8192
#define TPTS 16
#define NBLK 256   // persistent kernel: 1 block per CU (weakest co-residency req)

typedef unsigned short ushort_t;

// ---------------------------------------------------------------------------
// Wave (64-lane) sum reduction (valid result in lane 0)
// ---------------------------------------------------------------------------
__device__ __forceinline__ float wave_reduce64(float s) {
#pragma unroll
    for (int off = 32; off > 0; off >>= 1)
        s += __shfl_down(s, off, 64);
    return s;
}

// ---------------------------------------------------------------------------
// fp32 -> bf16 (RNE) packing, bf16x8 unpack
// ---------------------------------------------------------------------------
__device__ __forceinline__ unsigned f2bf_pack2(float lo, float hi) {
    unsigned ul = __float_as_uint(lo);
    unsigned uh = __float_as_uint(hi);
    ul = (ul + 0x7fffu + ((ul >> 16) & 1u)) >> 16;
    uh = (uh + 0x7fffu + ((uh >> 16) & 1u)) >> 16;
    return ul | (uh << 16);
}

__device__ __forceinline__ ushort_t bf16_1(float x) {
    unsigned u = __float_as_uint(x);
    return (ushort_t)((u + 0x7fffu + ((u >> 16) & 1u)) >> 16);
}

__device__ __forceinline__ void bf16x8_to_f32(uint4 w, float* f) {
    f[0] = __uint_as_float(w.x << 16); f[1] = __uint_as_float(w.x & 0xffff0000u);
    f[2] = __uint_as_float(w.y << 16); f[3] = __uint_as_float(w.y & 0xffff0000u);
    f[4] = __uint_as_float(w.z << 16); f[5] = __uint_as_float(w.z & 0xffff0000u);
    f[6] = __uint_as_float(w.w << 16); f[7] = __uint_as_float(w.w & 0xffff0000u);
}

// ===========================================================================
// PERSISTENT COOPERATIVE ODE KERNEL
// 256 blocks x 1024 threads (1 block/CU, 16 waves, 4 waves/EU -> 128 VGPR cap).
// Wave w owns row r = blockIdx*16 + w of BOTH W1 and W2, held as 2x32 NAMED
// scalar bf16x2 registers (64 VGPRs total) -- no arrays, nothing to spill.
// The 2-column (fwd/bwd) state vector travels through global as bf16x2
// (one uint per element: lo=fwd, hi=bwd) between matvecs, separated by a
// 2-level device-scope barrier; each block stages it into LDS (16 KB).
// Numerics identical to the validated multi-kernel bf16 path (bf16 weights,
// bf16 u at every stage, fp32 accumulation).
// ===========================================================================

// ---- 2-level grid barrier (16 leaves x 16 blocks). bar: 1024 uints, zeroed.
//      (identical to the structure proven on HW in the 256-block run)
__device__ __forceinline__ void grid_barrier(unsigned* bar) {
    __syncthreads();
    if (threadIdx.x == 0) {
        unsigned* leaf = bar + 32 * (blockIdx.x >> 4);
        unsigned* root = bar + 32 * 16;
        unsigned* gen  = bar + 32 * 17;
        unsigned g = __hip_atomic_load(gen, __ATOMIC_RELAXED, __HIP_MEMORY_SCOPE_AGENT);
        bool done = false;
        if (__hip_atomic_fetch_add(leaf, 1u, __ATOMIC_ACQ_REL, __HIP_MEMORY_SCOPE_AGENT) == 15u) {
            __hip_atomic_store(leaf, 0u, __ATOMIC_RELAXED, __HIP_MEMORY_SCOPE_AGENT);
            if (__hip_atomic_fetch_add(root, 1u, __ATOMIC_ACQ_REL, __HIP_MEMORY_SCOPE_AGENT) == 15u) {
                __hip_atomic_store(root, 0u, __ATOMIC_RELAXED, __HIP_MEMORY_SCOPE_AGENT);
                __hip_atomic_store(gen, g + 1u, __ATOMIC_RELEASE, __HIP_MEMORY_SCOPE_AGENT);
                done = true;
            }
        }
        if (!done) {
            while (__hip_atomic_load(gen, __ATOMIC_ACQUIRE, __HIP_MEMORY_SCOPE_AGENT) == g)
                __builtin_amdgcn_s_sleep(2);
        }
    }
    __syncthreads();
}

__global__ __launch_bounds__(64) void zero_bar(unsigned* bar) {
    for (int i = threadIdx.x; i < 1024; i += 64) bar[i] = 0;
}

// ---- X-macro over k = 0..31 --------------------------------------------
#define REP32(X) X(0) X(1) X(2) X(3) X(4) X(5) X(6) X(7) \
                 X(8) X(9) X(10) X(11) X(12) X(13) X(14) X(15) \
                 X(16) X(17) X(18) X(19) X(20) X(21) X(22) X(23) \
                 X(24) X(25) X(26) X(27) X(28) X(29) X(30) X(31)

#define DECL_W(K)  unsigned w1_##K, w2_##K;

// lane l, chunk K covers elements j0 = 2l + 128K, j1 = j0 + 1.
#define LOAD_W(K)  { float2 a_ = p0[l + 64 * K]; float2 c_ = q0[l + 64 * K]; \
                     w1_##K = f2bf_pack2(a_.x, a_.y);                        \
                     w2_##K = f2bf_pack2(c_.x, c_.y); }

// uS[j] = bf16x2 {lo=col0(fwd), hi=col1(bwd)} of element j.
// uB = uS + 2l; chunk K reads uint2 at +128K (bytes 8l + 512K, 8B aligned,
// consecutive-lane-consecutive-address = conflict-free b64).
#define DOT_1(K)   { uint2 uu_ = *(const uint2*)(uB + 128 * K);              \
                     float a0_ = __uint_as_float(uu_.x << 16);               \
                     float a1_ = __uint_as_float(uu_.x & 0xffff0000u);       \
                     float c0_ = __uint_as_float(uu_.y << 16);               \
                     float c1_ = __uint_as_float(uu_.y & 0xffff0000u);       \
                     float lo_ = __uint_as_float(w1_##K << 16);              \
                     float hi_ = __uint_as_float(w1_##K & 0xffff0000u);      \
                     s0 = fmaf(lo_, a0_, s0); s1 = fmaf(lo_, a1_, s1);       \
                     s0 = fmaf(hi_, c0_, s0); s1 = fmaf(hi_, c1_, s1); }

#define DOT_2(K)   { uint2 uu_ = *(const uint2*)(uB + 128 * K);              \
                     float a0_ = __uint_as_float(uu_.x << 16);               \
                     float a1_ = __uint_as_float(uu_.x & 0xffff0000u);       \
                     float c0_ = __uint_as_float(uu_.y << 16);               \
                     float c1_ = __uint_as_float(uu_.y & 0xffff0000u);       \
                     float lo_ = __uint_as_float(w2_##K << 16);              \
                     float hi_ = __uint_as_float(w2_##K & 0xffff0000u);      \
                     s0 = fmaf(lo_, a0_, s0); s1 = fmaf(lo_, a1_, s1);       \
                     s0 = fmaf(hi_, c0_, s0); s1 = fmaf(hi_, c1_, s1); }

__global__ __launch_bounds__(1024, 4) void ode_persistent(
    const float* __restrict__ W1, const float* __restrict__ b1,
    const float* __restrict__ W2, const float* __restrict__ b2,
    const float* __restrict__ h_f, const float* __restrict__ h_b,
    const float* __restrict__ tf, const float* __restrict__ tb,
    unsigned* __restrict__ Ugu, unsigned* __restrict__ Vgu,
    unsigned* __restrict__ bar, float* __restrict__ Hg)
{
    __shared__ unsigned uS[NH];   // 16 KB: bf16x2 (fwd,bwd) per element
    const int t   = threadIdx.x;  // 0..1023
    const int l   = t & 63;
    const int w   = t >> 6;       // 0..15
    const int row = blockIdx.x * 16 + w;

    // ---- this wave's weight row of W1 and W2 -> named registers ----
    REP32(DECL_W)
    {
        const float2* p0 = (const float2*)(W1 + (size_t)row * NH);
        const float2* q0 = (const float2*)(W2 + (size_t)row * NH);
        REP32(LOAD_W)
    }

    // ---- initial u = bf16(h0), staged straight from inputs ----
    {
        const float4* hf4 = (const float4*)h_f;
        const float4* hb4 = (const float4*)h_b;
        float4 a = hf4[t];
        float4 b = hb4[t];
        uint4 o;
        o.x = f2bf_pack2(a.x, b.x);
        o.y = f2bf_pack2(a.y, b.y);
        o.z = f2bf_pack2(a.z, b.z);
        o.w = f2bf_pack2(a.w, b.w);
        ((uint4*)uS)[t] = o;
    }

    float H0 = h_f[row], H1 = h_b[row];
    const float bb1 = b1[row];
    const float bb2 = b2[row];
    float A0 = 0.f, A1 = 0.f;
    const unsigned* uB = uS + 2 * l;

    __syncthreads();

    for (int s = 0; s < TPTS - 1; ++s) {
        const float dt0 = tf[s + 1] - tf[s];
        const float dt1 = tb[s + 1] - tb[s];
        for (int st = 0; st < 4; ++st) {
            float s0, s1;

            // === mv1: v = tanh(W1 u + b1) ===
            s0 = 0.f; s1 = 0.f;
            REP32(DOT_1)
            s0 = wave_reduce64(s0); s1 = wave_reduce64(s1);
            if (l == 0)
                Vgu[row] = f2bf_pack2(tanhf(s0 + bb1), tanhf(s1 + bb1));
            grid_barrier(bar);
            ((uint4*)uS)[t] = ((const uint4*)Vgu)[t];   // restage v
            __syncthreads();

            // === mv2: k = W2 v + b2; RK4 accumulate; publish next u ===
            s0 = 0.f; s1 = 0.f;
            REP32(DOT_2)
            s0 = wave_reduce64(s0); s1 = wave_reduce64(s1);
            {
                float k0 = s0 + bb2, k1 = s1 + bb2;
                float wgt = (st == 1 || st == 2) ? 2.f : 1.f;
                if (st == 0) { A0 = H0; A1 = H1; }
                A0 += wgt * (dt0 / 6.f) * k0;
                A1 += wgt * (dt1 / 6.f) * k1;
                float u0, u1;
                if (st == 3) {
                    H0 = A0; H1 = A1;
                    u0 = H0; u1 = H1;
                } else {
                    float cn = (st == 2) ? 1.f : 0.5f;
                    u0 = H0 + cn * dt0 * k0;
                    u1 = H1 + cn * dt1 * k1;
                }
                if (l == 0) Ugu[row] = f2bf_pack2(u0, u1);
            }
            grid_barrier(bar);
            ((uint4*)uS)[t] = ((const uint4*)Ugu)[t];   // restage u
            __syncthreads();
        }
    }

    // final h -> Hg (fp32) for the GRU/head tail
    if (l == 0) {
        Hg[row]      = H0;
        Hg[NH + row] = H1;
    }
}

// ===========================================================================
// Fallback path kernels (previous harness-verified version, unchanged)
// ===========================================================================

__global__ __launch_bounds__(256) void cvt_bf16_kernel(const float* __restrict__ src,
                                                       ushort_t* __restrict__ dst, int n8) {
    int i = blockIdx.x * 256 + threadIdx.x;
    if (i < n8) {
        const float4* s4 = (const float4*)src;
        float4 a = s4[2 * i], b = s4[2 * i + 1];
        uint4 o;
        o.x = f2bf_pack2(a.x, a.y);
        o.y = f2bf_pack2(a.z, a.w);
        o.z = f2bf_pack2(b.x, b.y);
        o.w = f2bf_pack2(b.z, b.w);
        ((uint4*)dst)[i] = o;
    }
}

__global__ __launch_bounds__(256) void init_hu(const float* __restrict__ h_f,
                                               const float* __restrict__ h_b,
                                               float* __restrict__ H,
                                               ushort_t* __restrict__ Ubf) {
    int i = blockIdx.x * 256 + threadIdx.x;
    float a = h_f[i], b = h_b[i];
    H[i]       = a;  H[NH + i]   = b;
    Ubf[i]     = bf16_1(a);
    Ubf[NH + i] = bf16_1(b);
}

__global__ __launch_bounds__(512, 4) void ode_mv1(
    const ushort_t* __restrict__ W1b, const float* __restrict__ b1,
    const ushort_t* __restrict__ Ubf, ushort_t* __restrict__ Vbf)
{
    __shared__ uint4 uS[1024];
    const int t = threadIdx.x;
    {
        const uint4* U4 = (const uint4*)Ubf;
        uS[t]       = U4[t];
        uS[t + 512] = U4[t + 512];
    }
    __syncthreads();

    const int l   = t & 63;
    const int row = blockIdx.x * 8 + (t >> 6);
    const uint4* __restrict__ W4 = (const uint4*)(W1b + (size_t)row * NH);

    float s0 = 0.f, s1 = 0.f;
#pragma unroll
    for (int i = 0; i < 8; ++i) {
        int idx = l + 64 * i;
        uint4 wv = W4[idx];
        uint4 u0 = uS[idx];
        uint4 u1 = uS[512 + idx];
        float wf[8], a0[8], a1[8];
        bf16x8_to_f32(wv, wf);
        bf16x8_to_f32(u0, a0);
        bf16x8_to_f32(u1, a1);
#pragma unroll
        for (int k = 0; k < 8; ++k) {
            s0 += wf[k] * a0[k];
            s1 += wf[k] * a1[k];
        }
    }
    s0 = wave_reduce64(s0);
    s1 = wave_reduce64(s1);
    if (l == 0) {
        float bb = b1[row];
        Vbf[row]      = bf16_1(tanhf(s0 + bb));
        Vbf[NH + row] = bf16_1(tanhf(s1 + bb));
    }
}

__global__ __launch_bounds__(512, 4) void ode_mv2(
    const ushort_t* __restrict__ W2b, const float* __restrict__ b2,
    const ushort_t* __restrict__ Vbf,
    const float* __restrict__ tf, const float* __restrict__ tb, int sidx,
    float wgt, float cnext, int stage,
    float* __restrict__ H, float* __restrict__ ACC,
    ushort_t* __restrict__ Ubf)
{
    __shared__ uint4 vS[1024];
    const int t = threadIdx.x;
    {
        const uint4* V4 = (const uint4*)Vbf;
        vS[t]       = V4[t];
        vS[t + 512] = V4[t + 512];
    }
    __syncthreads();

    const int l   = t & 63;
    const int row = blockIdx.x * 8 + (t >> 6);
    const uint4* __restrict__ W4 = (const uint4*)(W2b + (size_t)row * NH);
    const float dt0 = tf[sidx + 1] - tf[sidx];
    const float dt1 = tb[sidx + 1] - tb[sidx];

    float s0 = 0.f, s1 = 0.f;
#pragma unroll
    for (int i = 0; i < 8; ++i) {
        int idx = l + 64 * i;
        uint4 wv = W4[idx];
        uint4 v0 = vS[idx];
        uint4 v1 = vS[512 + idx];
        float wf[8], a0[8], a1[8];
        bf16x8_to_f32(wv, wf);
        bf16x8_to_f32(v0, a0);
        bf16x8_to_f32(v1, a1);
#pragma unroll
        for (int k = 0; k < 8; ++k) {
            s0 += wf[k] * a0[k];
            s1 += wf[k] * a1[k];
        }
    }
    s0 = wave_reduce64(s0);
    s1 = wave_reduce64(s1);
    if (l == 0) {
        float bb = b2[row];
        float k0 = s0 + bb, k1 = s1 + bb;
        float base0 = (stage == 0) ? H[row]      : ACC[row];
        float base1 = (stage == 0) ? H[NH + row] : ACC[NH + row];
        float a0 = base0 + wgt * (dt0 / 6.f) * k0;
        float a1 = base1 + wgt * (dt1 / 6.f) * k1;
        ACC[row]      = a0;
        ACC[NH + row] = a1;
        if (stage == 3) {
            H[row]      = a0;
            H[NH + row] = a1;
            Ubf[row]      = bf16_1(a0);
            Ubf[NH + row] = bf16_1(a1);
        } else {
            Ubf[row]      = bf16_1(H[row]      + cnext * dt0 * k0);
            Ubf[NH + row] = bf16_1(H[NH + row] + cnext * dt1 * k1);
        }
    }
}

__global__ __launch_bounds__(256) void init_h_kernel(const float* __restrict__ h_f,
                                                     const float* __restrict__ h_b,
                                                     float* __restrict__ H) {
    int i = blockIdx.x * 256 + threadIdx.x;
    H[i]      = h_f[i];
    H[NH + i] = h_b[i];
}

__global__ __launch_bounds__(256) void rk4_mv1_f32(
    const float* __restrict__ W1, const float* __restrict__ b1,
    const float* __restrict__ H,  const float* __restrict__ Kv,
    const float* __restrict__ tf, const float* __restrict__ tb,
    int tidx, float coef, int useK,
    float* __restrict__ V)
{
    const int row  = blockIdx.x * 4 + (threadIdx.x >> 6);
    const int lane = threadIdx.x & 63;
    const float a0 = coef * (tf[tidx + 1] - tf[tidx]);
    const float a1 = coef * (tb[tidx + 1] - tb[tidx]);

    const float4* __restrict__ W4 = (const float4*)(W1 + (size_t)row * NH);
    const float4* __restrict__ x0 = (const float4*)(H);
    const float4* __restrict__ x1 = (const float4*)(H + NH);
    const float4* __restrict__ k0 = (const float4*)(Kv);
    const float4* __restrict__ k1 = (const float4*)(Kv + NH);

    float s0 = 0.f, s1 = 0.f;
    if (useK) {
#pragma unroll 8
        for (int i = 0; i < NH / 4 / 64; ++i) {
            int idx = lane + i * 64;
            float4 w  = W4[idx];
            float4 h0 = x0[idx], h1 = x1[idx];
            float4 p0 = k0[idx], p1 = k1[idx];
            s0 += w.x * (h0.x + a0 * p0.x) + w.y * (h0.y + a0 * p0.y)
                + w.z * (h0.z + a0 * p0.z) + w.w * (h0.w + a0 * p0.w);
            s1 += w.x * (h1.x + a1 * p1.x) + w.y * (h1.y + a1 * p1.y)
                + w.z * (h1.z + a1 * p1.z) + w.w * (h1.w + a1 * p1.w);
        }
    } else {
#pragma unroll 8
        for (int i = 0; i < NH / 4 / 64; ++i) {
            int idx = lane + i * 64;
            float4 w  = W4[idx];
            float4 h0 = x0[idx], h1 = x1[idx];
            s0 += w.x * h0.x + w.y * h0.y + w.z * h0.z + w.w * h0.w;
            s1 += w.x * h1.x + w.y * h1.y + w.z * h1.z + w.w * h1.w;
        }
    }
    s0 = wave_reduce64(s0);
    s1 = wave_reduce64(s1);
    if (lane == 0) {
        float bb = b1[row];
        V[row]      = tanhf(s0 + bb);
        V[NH + row] = tanhf(s1 + bb);
    }
}

__global__ __launch_bounds__(256) void rk4_mv2_f32(
    const float* __restrict__ W2, const float* __restrict__ b2,
    const float* __restrict__ V,
    const float* __restrict__ tf, const float* __restrict__ tb,
    int tidx, float wgt,
    const float* __restrict__ Hbase,
    float* __restrict__ Kout, float* __restrict__ ACC)
{
    const int row  = blockIdx.x * 4 + (threadIdx.x >> 6);
    const int lane = threadIdx.x & 63;

    const float4* __restrict__ W4 = (const float4*)(W2 + (size_t)row * NH);
    const float4* __restrict__ v0 = (const float4*)(V);
    const float4* __restrict__ v1 = (const float4*)(V + NH);

    float s0 = 0.f, s1 = 0.f;
#pragma unroll 8
    for (int i = 0; i < NH / 4 / 64; ++i) {
        int idx = lane + i * 64;
        float4 w = W4[idx];
        float4 a = v0[idx], b = v1[idx];
        s0 += w.x * a.x + w.y * a.y + w.z * a.z + w.w * a.w;
        s1 += w.x * b.x + w.y * b.y + w.z * b.z + w.w * b.w;
    }
    s0 = wave_reduce64(s0);
    s1 = wave_reduce64(s1);
    if (lane == 0) {
        float bb  = b2[row];
        float k0v = s0 + bb;
        float k1v = s1 + bb;
        Kout[row]      = k0v;
        Kout[NH + row] = k1v;
        const float dt0 = tf[tidx + 1] - tf[tidx];
        const float dt1 = tb[tidx + 1] - tb[tidx];
        ACC[row]      = Hbase[row]      + wgt * (dt0 / 6.f) * k0v;
        ACC[NH + row] = Hbase[NH + row] + wgt * (dt1 / 6.f) * k1v;
    }
}

// ---------------------------------------------------------------------------
// GRU / head kernels (fp32 weights; used 1-2x each)
// ---------------------------------------------------------------------------
__global__ __launch_bounds__(256) void build_xcat_kernel(
    const float* __restrict__ x_f, const float* __restrict__ x_b,
    const float* __restrict__ H,
    float* __restrict__ xcat1, float* __restrict__ xcat2)
{
    int i = blockIdx.x * 256 + threadIdx.x;
    float xf = x_f[i], xb = x_b[i];
    xcat1[i]               = xf;
    xcat2[i]               = xf;
    xcat1[KCAT + i]        = xb;
    xcat2[KCAT + i]        = xb;
    xcat1[NH + i]          = H[i];
    xcat1[KCAT + NH + i]   = H[NH + i];
}

__global__ __launch_bounds__(256) void gru_mv1(
    const float* __restrict__ Wi, const float* __restrict__ bi,
    const float* __restrict__ xcat1, const float* __restrict__ H,
    float* __restrict__ G, float* __restrict__ xcat2)
{
    const int row  = blockIdx.x * 4 + (threadIdx.x >> 6);
    const int lane = threadIdx.x & 63;

    const float4* __restrict__ W4 = (const float4*)(Wi + (size_t)row * KCAT);
    const float4* __restrict__ c0 = (const float4*)(xcat1);
    const float4* __restrict__ c1 = (const float4*)(xcat1 + KCAT);

    float s0 = 0.f, s1 = 0.f;
#pragma unroll 8
    for (int i = 0; i < KCAT / 4 / 64; ++i) {
        int idx = lane + i * 64;
        float4 w = W4[idx];
        float4 a = c0[idx], b = c1[idx];
        s0 += w.x * a.x + w.y * a.y + w.z * a.z + w.w * a.w;
        s1 += w.x * b.x + w.y * b.y + w.z * b.z + w.w * b.w;
    }
    s0 = wave_reduce64(s0);
    s1 = wave_reduce64(s1);
    if (lane == 0) {
        float bb = bi[row];
        float g0 = 1.f / (1.f + expf(-(s0 + bb)));
        float g1 = 1.f / (1.f + expf(-(s1 + bb)));
        G[row]      = g0;
        G[NH + row] = g1;
        xcat2[NH + row]        = g0 * H[row];
        xcat2[KCAT + NH + row] = g1 * H[NH + row];
    }
}

__global__ __launch_bounds__(256) void gru_mv2(
    const float* __restrict__ Wi, const float* __restrict__ bi,
    const float* __restrict__ xcat2, const float* __restrict__ H,
    const float* __restrict__ G,
    float* __restrict__ out, float* __restrict__ hcat)
{
    const int row  = blockIdx.x * 4 + (threadIdx.x >> 6);
    const int lane = threadIdx.x & 63;

    const float4* __restrict__ W4 = (const float4*)(Wi + (size_t)row * KCAT);
    const float4* __restrict__ c0 = (const float4*)(xcat2);
    const float4* __restrict__ c1 = (const float4*)(xcat2 + KCAT);

    float s0 = 0.f, s1 = 0.f;
#pragma unroll 8
    for (int i = 0; i < KCAT / 4 / 64; ++i) {
        int idx = lane + i * 64;
        float4 w = W4[idx];
        float4 a = c0[idx], b = c1[idx];
        s0 += w.x * a.x + w.y * a.y + w.z * a.z + w.w * a.w;
        s1 += w.x * b.x + w.y * b.y + w.z * b.z + w.w * b.w;
    }
    s0 = wave_reduce64(s0);
    s1 = wave_reduce64(s1);
    if (lane == 0) {
        float bb  = bi[row];
        float hh0 = tanhf(s0 + bb);
        float hh1 = tanhf(s1 + bb);
        float g0  = G[row], g1 = G[NH + row];
        float hf  = g0 * H[row]      + (1.f - g0) * hh0;
        float hb  = g1 * H[NH + row] + (1.f - g1) * hh1;
        out[NH + row]     = hf;
        out[2 * NH + row] = hb;
        hcat[row]      = hf;
        hcat[NH + row] = hb;
    }
}

__global__ __launch_bounds__(256) void h2o_mv(
    const float* __restrict__ W, const float* __restrict__ b,
    const float* __restrict__ hcat, float* __restrict__ out)
{
    const int row  = blockIdx.x * 4 + (threadIdx.x >> 6);
    const int lane = threadIdx.x & 63;

    const float4* __restrict__ W4 = (const float4*)(W + (size_t)row * KCAT);
    const float4* __restrict__ x4 = (const float4*)(hcat);

    float s = 0.f;
#pragma unroll 8
    for (int i = 0; i < KCAT / 4 / 64; ++i) {
        int idx = lane + i * 64;
        float4 w = W4[idx];
        float4 a = x4[idx];
        s += w.x * a.x + w.y * a.y + w.z * a.z + w.w * a.w;
    }
    s = wave_reduce64(s);
    if (lane == 0)
        out[row] = s + b[row];
}

// ---------------------------------------------------------------------------
extern "C" void kernel_launch(void* const* d_in, const int* in_sizes, int n_in,
                              void* d_out, int out_size, void* d_ws, size_t ws_size,
                              hipStream_t stream) {
    const float* x_f   = (const float*)d_in[0];
    const float* x_b   = (const float*)d_in[1];
    const float* h_f   = (const float*)d_in[2];
    const float* h_b   = (const float*)d_in[3];
    const float* t_f   = (const float*)d_in[4];
    const float* t_b   = (const float*)d_in[5];
    const float* i2h_W = (const float*)d_in[6];
    const float* i2h_b = (const float*)d_in[7];
    const float* h2o_W = (const float*)d_in[8];
    const float* h2o_b = (const float*)d_in[9];
    const float* f_W1  = (const float*)d_in[10];
    const float* f_b1  = (const float*)d_in[11];
    const float* f_W2  = (const float*)d_in[12];
    const float* f_b2  = (const float*)d_in[13];
    float* out = (float*)d_out;

    // ---- workspace layout (all offsets 16B-aligned) ----
    float* ws    = (float*)d_ws;
    float* Hg    = ws;                  // 2*NH fp32
    float* ACCg  = Hg    + 2 * NH;      // 2*NH fp32
    float* Vg32  = ACCg  + 2 * NH;      // 2*NH fp32 (fallback V)
    float* Kg32  = Vg32  + 2 * NH;      // 2*NH fp32 (fallback K)
    float* xcat1 = Kg32  + 2 * NH;      // 2*KCAT
    float* xcat2 = xcat1 + 2 * KCAT;    // 2*KCAT
    float* G     = xcat2 + 2 * KCAT;    // 2*NH
    float* hcat  = G     + 2 * NH;      // KCAT
    float* fend  = hcat  + KCAT;
    ushort_t* Ubf = (ushort_t*)fend;            // 2*NH bf16 (16 KB)
    ushort_t* Vbf = Ubf + 2 * NH;               // 2*NH bf16 (16 KB)
    ushort_t* W1b = Vbf + 2 * NH;               // NH*NH bf16 (32 MB, fallback only)
    ushort_t* W2b = W1b + (size_t)NH * NH;      // NH*NH bf16 (32 MB, fallback only)
    size_t need = (size_t)((char*)(W2b + (size_t)NH * NH) - (char*)d_ws);
    const bool fast = ws_size >= need;

    // coop-path buffers alias the (unused-in-coop) W1b region
    unsigned* Ugu  = (unsigned*)W1b;               // NH uints (16 KB)
    unsigned* Vgu  = Ugu + NH;                     // NH uints (16 KB)
    unsigned* barp = Vgu + NH;                     // 1024 uints (4 KB)
    size_t coop_need = (size_t)((char*)(barp + 1024) - (char*)d_ws);

    dim3 blk(256);

    bool ode_done = false;
    if (ws_size >= coop_need) {
        zero_bar<<<1, 64, 0, stream>>>(barp);
        void* kargs[] = { (void*)&f_W1, (void*)&f_b1, (void*)&f_W2, (void*)&f_b2,
                          (void*)&h_f,  (void*)&h_b,  (void*)&t_f,  (void*)&t_b,
                          (void*)&Ugu,  (void*)&Vgu,  (void*)&barp, (void*)&Hg };
        hipError_t e = hipLaunchCooperativeKernel(ode_persistent, dim3(NBLK), dim3(1024),
                                                  kargs, 0, stream);
        ode_done = (e == hipSuccess);
    }

    if (!ode_done) {
        if (fast) {
            const int n8 = NH * NH / 8;
            cvt_bf16_kernel<<<n8 / 256, blk, 0, stream>>>(f_W1, W1b, n8);
            cvt_bf16_kernel<<<n8 / 256, blk, 0, stream>>>(f_W2, W2b, n8);
            init_hu<<<NH / 256, blk, 0, stream>>>(h_f, h_b, Hg, Ubf);

            for (int s = 0; s < TPTS - 1; ++s) {
                ode_mv1<<<512, 512, 0, stream>>>(W1b, f_b1, Ubf, Vbf);
                ode_mv2<<<512, 512, 0, stream>>>(W2b, f_b2, Vbf, t_f, t_b, s,
                                                 1.f, 0.5f, 0, Hg, ACCg, Ubf);
                ode_mv1<<<512, 512, 0, stream>>>(W1b, f_b1, Ubf, Vbf);
                ode_mv2<<<512, 512, 0, stream>>>(W2b, f_b2, Vbf, t_f, t_b, s,
                                                 2.f, 0.5f, 1, Hg, ACCg, Ubf);
                ode_mv1<<<512, 512, 0, stream>>>(W1b, f_b1, Ubf, Vbf);
                ode_mv2<<<512, 512, 0, stream>>>(W2b, f_b2, Vbf, t_f, t_b, s,
                                                 2.f, 1.0f, 2, Hg, ACCg, Ubf);
                ode_mv1<<<512, 512, 0, stream>>>(W1b, f_b1, Ubf, Vbf);
                ode_mv2<<<512, 512, 0, stream>>>(W2b, f_b2, Vbf, t_f, t_b, s,
                                                 1.f, 0.0f, 3, Hg, ACCg, Ubf);
            }
        } else {
            const int mv_grid = NH / 4;
            init_h_kernel<<<NH / 256, blk, 0, stream>>>(h_f, h_b, Hg);
            float* H   = Hg;
            float* ACC = ACCg;
            for (int s = 0; s < TPTS - 1; ++s) {
                rk4_mv1_f32<<<mv_grid, blk, 0, stream>>>(f_W1, f_b1, H, Kg32, t_f, t_b, s, 0.0f, 0, Vg32);
                rk4_mv2_f32<<<mv_grid, blk, 0, stream>>>(f_W2, f_b2, Vg32, t_f, t_b, s, 1.0f, H,   Kg32, ACC);
                rk4_mv1_f32<<<mv_grid, blk, 0, stream>>>(f_W1, f_b1, H, Kg32, t_f, t_b, s, 0.5f, 1, Vg32);
                rk4_mv2_f32<<<mv_grid, blk, 0, stream>>>(f_W2, f_b2, Vg32, t_f, t_b, s, 2.0f, ACC, Kg32, ACC);
                rk4_mv1_f32<<<mv_grid, blk, 0, stream>>>(f_W1, f_b1, H, Kg32, t_f, t_b, s, 0.5f, 1, Vg32);
                rk4_mv2_f32<<<mv_grid, blk, 0, stream>>>(f_W2, f_b2, Vg32, t_f, t_b, s, 2.0f, ACC, Kg32, ACC);
                rk4_mv1_f32<<<mv_grid, blk, 0, stream>>>(f_W1, f_b1, H, Kg32, t_f, t_b, s, 1.0f, 1, Vg32);
                rk4_mv2_f32<<<mv_grid, blk, 0, stream>>>(f_W2, f_b2, Vg32, t_f, t_b, s, 1.0f, ACC, Kg32, ACC);
                float* tmp = H; H = ACC; ACC = tmp;
            }
            if (H != Hg) {
                hipMemcpyAsync(Hg, H, 2 * NH * sizeof(float), hipMemcpyDeviceToDevice, stream);
            }
        }
    }

    const int mv_grid = NH / 4;
    build_xcat_kernel<<<NH / 256, blk, 0, stream>>>(x_f, x_b, Hg, xcat1, xcat2);
    gru_mv1<<<mv_grid, blk, 0, stream>>>(i2h_W, i2h_b, xcat1, Hg, G, xcat2);
    gru_mv2<<<mv_grid, blk, 0, stream>>>(i2h_W, i2h_b, xcat2, Hg, G, out, hcat);
    h2o_mv <<<mv_grid, blk, 0, stream>>>(h2o_W, h2o_b, hcat, out);
}

// Round 4
// 2998.190 us; speedup vs baseline: 1.4934x; 1.4934x over previous
//
#include <hip/hip_runtime.h>
#include <math.h>

#define NH   4096
#define KCAT 8192
#define TPTS 16
#define NBLK 256   // persistent kernel: 1 block per CU (weakest co-residency req)

typedef unsigned short ushort_t;

// ---------------------------------------------------------------------------
// Wave (64-lane) sum reduction (valid result in lane 0)
// ---------------------------------------------------------------------------
__device__ __forceinline__ float wave_reduce64(float s) {
#pragma unroll
    for (int off = 32; off > 0; off >>= 1)
        s += __shfl_down(s, off, 64);
    return s;
}

// ---------------------------------------------------------------------------
// fp32 -> bf16 (RNE) packing, bf16x8 unpack
// ---------------------------------------------------------------------------
__device__ __forceinline__ unsigned f2bf_pack2(float lo, float hi) {
    unsigned ul = __float_as_uint(lo);
    unsigned uh = __float_as_uint(hi);
    ul = (ul + 0x7fffu + ((ul >> 16) & 1u)) >> 16;
    uh = (uh + 0x7fffu + ((uh >> 16) & 1u)) >> 16;
    return ul | (uh << 16);
}

__device__ __forceinline__ ushort_t bf16_1(float x) {
    unsigned u = __float_as_uint(x);
    return (ushort_t)((u + 0x7fffu + ((u >> 16) & 1u)) >> 16);
}

__device__ __forceinline__ void bf16x8_to_f32(uint4 w, float* f) {
    f[0] = __uint_as_float(w.x << 16); f[1] = __uint_as_float(w.x & 0xffff0000u);
    f[2] = __uint_as_float(w.y << 16); f[3] = __uint_as_float(w.y & 0xffff0000u);
    f[4] = __uint_as_float(w.z << 16); f[5] = __uint_as_float(w.z & 0xffff0000u);
    f[6] = __uint_as_float(w.w << 16); f[7] = __uint_as_float(w.w & 0xffff0000u);
}

// ===========================================================================
// PERSISTENT COOPERATIVE ODE KERNEL
// 256 blocks x 1024 threads (1 block/CU, 16 waves, 4 waves/EU -> 128 VGPR cap).
// Wave w owns row r = blockIdx*16 + w of BOTH W1 and W2, held as 2x32 NAMED
// scalar bf16x2 registers (64 VGPRs total).
//
// ROUND-3 LESSON: naming alone is not enough -- the compiler SANK the weight
// loads back into the loop (W1/W2 are const, so re-loading is legal and
// cheaper on registers; VGPR_Count=64, FETCH=3.8GB proved it). The KEEPW asm
// below claims to read-modify every weight register EACH stage iteration,
// making re-materialization from global illegal. Forces true residency.
//
// The 2-column (fwd/bwd) state vector travels through global as bf16x2
// (one uint per element: lo=fwd, hi=bwd) between matvecs, separated by a
// 2-level device-scope barrier; each block stages it into LDS (16 KB).
// ===========================================================================

// ---- 2-level grid barrier (16 leaves x 16 blocks). bar: 1024 uints, zeroed.
__device__ __forceinline__ void grid_barrier(unsigned* bar) {
    __syncthreads();
    if (threadIdx.x == 0) {
        unsigned* leaf = bar + 32 * (blockIdx.x >> 4);
        unsigned* root = bar + 32 * 16;
        unsigned* gen  = bar + 32 * 17;
        unsigned g = __hip_atomic_load(gen, __ATOMIC_RELAXED, __HIP_MEMORY_SCOPE_AGENT);
        bool done = false;
        if (__hip_atomic_fetch_add(leaf, 1u, __ATOMIC_ACQ_REL, __HIP_MEMORY_SCOPE_AGENT) == 15u) {
            __hip_atomic_store(leaf, 0u, __ATOMIC_RELAXED, __HIP_MEMORY_SCOPE_AGENT);
            if (__hip_atomic_fetch_add(root, 1u, __ATOMIC_ACQ_REL, __HIP_MEMORY_SCOPE_AGENT) == 15u) {
                __hip_atomic_store(root, 0u, __ATOMIC_RELAXED, __HIP_MEMORY_SCOPE_AGENT);
                __hip_atomic_store(gen, g + 1u, __ATOMIC_RELEASE, __HIP_MEMORY_SCOPE_AGENT);
                done = true;
            }
        }
        if (!done) {
            while (__hip_atomic_load(gen, __ATOMIC_ACQUIRE, __HIP_MEMORY_SCOPE_AGENT) == g)
                __builtin_amdgcn_s_sleep(2);
        }
    }
    __syncthreads();
}

__global__ __launch_bounds__(64) void zero_bar(unsigned* bar) {
    for (int i = threadIdx.x; i < 1024; i += 64) bar[i] = 0;
}

// ---- X-macro over k = 0..31 --------------------------------------------
#define REP32(X) X(0) X(1) X(2) X(3) X(4) X(5) X(6) X(7) \
                 X(8) X(9) X(10) X(11) X(12) X(13) X(14) X(15) \
                 X(16) X(17) X(18) X(19) X(20) X(21) X(22) X(23) \
                 X(24) X(25) X(26) X(27) X(28) X(29) X(30) X(31)

#define DECL_W(K)  unsigned w1_##K, w2_##K;

// lane l, chunk K covers elements j0 = 2l + 128K, j1 = j0 + 1.
#define LOAD_W(K)  { float2 a_ = p0[l + 64 * K]; float2 c_ = q0[l + 64 * K]; \
                     w1_##K = f2bf_pack2(a_.x, a_.y);                        \
                     w2_##K = f2bf_pack2(c_.x, c_.y); }

// Residency fence: pretend to read+modify each weight register. Zero
// instructions, but makes global-load rematerialization illegal and pins
// the value in a VGPR across the loop body.
#define KEEPW(K)   asm volatile("" : "+v"(w1_##K), "+v"(w2_##K));

// uS[j] = bf16x2 {lo=col0(fwd), hi=col1(bwd)} of element j.
// uB = uS + 2l; chunk K reads uint2 at +128K (bytes 8l + 512K, 8B aligned,
// consecutive-lane-consecutive-address = conflict-free b64).
#define DOT_1(K)   { uint2 uu_ = *(const uint2*)(uB + 128 * K);              \
                     float a0_ = __uint_as_float(uu_.x << 16);               \
                     float a1_ = __uint_as_float(uu_.x & 0xffff0000u);       \
                     float c0_ = __uint_as_float(uu_.y << 16);               \
                     float c1_ = __uint_as_float(uu_.y & 0xffff0000u);       \
                     float lo_ = __uint_as_float(w1_##K << 16);              \
                     float hi_ = __uint_as_float(w1_##K & 0xffff0000u);      \
                     s0 = fmaf(lo_, a0_, s0); s1 = fmaf(lo_, a1_, s1);       \
                     s0 = fmaf(hi_, c0_, s0); s1 = fmaf(hi_, c1_, s1); }

#define DOT_2(K)   { uint2 uu_ = *(const uint2*)(uB + 128 * K);              \
                     float a0_ = __uint_as_float(uu_.x << 16);               \
                     float a1_ = __uint_as_float(uu_.x & 0xffff0000u);       \
                     float c0_ = __uint_as_float(uu_.y << 16);               \
                     float c1_ = __uint_as_float(uu_.y & 0xffff0000u);       \
                     float lo_ = __uint_as_float(w2_##K << 16);              \
                     float hi_ = __uint_as_float(w2_##K & 0xffff0000u);      \
                     s0 = fmaf(lo_, a0_, s0); s1 = fmaf(lo_, a1_, s1);       \
                     s0 = fmaf(hi_, c0_, s0); s1 = fmaf(hi_, c1_, s1); }

__global__ __launch_bounds__(1024, 4) void ode_persistent(
    const float* __restrict__ W1, const float* __restrict__ b1,
    const float* __restrict__ W2, const float* __restrict__ b2,
    const float* __restrict__ h_f, const float* __restrict__ h_b,
    const float* __restrict__ tf, const float* __restrict__ tb,
    unsigned* __restrict__ Ugu, unsigned* __restrict__ Vgu,
    unsigned* __restrict__ bar, float* __restrict__ Hg)
{
    __shared__ unsigned uS[NH];   // 16 KB: bf16x2 (fwd,bwd) per element
    const int t   = threadIdx.x;  // 0..1023
    const int l   = t & 63;
    const int w   = t >> 6;       // 0..15
    const int row = blockIdx.x * 16 + w;

    // ---- this wave's weight row of W1 and W2 -> named registers ----
    REP32(DECL_W)
    {
        const float2* p0 = (const float2*)(W1 + (size_t)row * NH);
        const float2* q0 = (const float2*)(W2 + (size_t)row * NH);
        REP32(LOAD_W)
    }

    // ---- initial u = bf16(h0), staged straight from inputs ----
    {
        const float4* hf4 = (const float4*)h_f;
        const float4* hb4 = (const float4*)h_b;
        float4 a = hf4[t];
        float4 b = hb4[t];
        uint4 o;
        o.x = f2bf_pack2(a.x, b.x);
        o.y = f2bf_pack2(a.y, b.y);
        o.z = f2bf_pack2(a.z, b.z);
        o.w = f2bf_pack2(a.w, b.w);
        ((uint4*)uS)[t] = o;
    }

    float H0 = h_f[row], H1 = h_b[row];
    const float bb1 = b1[row];
    const float bb2 = b2[row];
    float A0 = 0.f, A1 = 0.f;
    const unsigned* uB = uS + 2 * l;

    __syncthreads();

    for (int s = 0; s < TPTS - 1; ++s) {
        const float dt0 = tf[s + 1] - tf[s];
        const float dt1 = tb[s + 1] - tb[s];
        for (int st = 0; st < 4; ++st) {
            float s0, s1;

            // pin all weight registers (see header comment) -- no codegen
            REP32(KEEPW)

            // === mv1: v = tanh(W1 u + b1) ===
            s0 = 0.f; s1 = 0.f;
            REP32(DOT_1)
            s0 = wave_reduce64(s0); s1 = wave_reduce64(s1);
            if (l == 0)
                Vgu[row] = f2bf_pack2(tanhf(s0 + bb1), tanhf(s1 + bb1));
            grid_barrier(bar);
            ((uint4*)uS)[t] = ((const uint4*)Vgu)[t];   // restage v
            __syncthreads();

            // === mv2: k = W2 v + b2; RK4 accumulate; publish next u ===
            s0 = 0.f; s1 = 0.f;
            REP32(DOT_2)
            s0 = wave_reduce64(s0); s1 = wave_reduce64(s1);
            {
                float k0 = s0 + bb2, k1 = s1 + bb2;
                float wgt = (st == 1 || st == 2) ? 2.f : 1.f;
                if (st == 0) { A0 = H0; A1 = H1; }
                A0 += wgt * (dt0 / 6.f) * k0;
                A1 += wgt * (dt1 / 6.f) * k1;
                float u0, u1;
                if (st == 3) {
                    H0 = A0; H1 = A1;
                    u0 = H0; u1 = H1;
                } else {
                    float cn = (st == 2) ? 1.f : 0.5f;
                    u0 = H0 + cn * dt0 * k0;
                    u1 = H1 + cn * dt1 * k1;
                }
                if (l == 0) Ugu[row] = f2bf_pack2(u0, u1);
            }
            grid_barrier(bar);
            ((uint4*)uS)[t] = ((const uint4*)Ugu)[t];   // restage u
            __syncthreads();
        }
    }

    // final h -> Hg (fp32) for the GRU/head tail
    if (l == 0) {
        Hg[row]      = H0;
        Hg[NH + row] = H1;
    }
}

// ===========================================================================
// Fallback path kernels (previous harness-verified version, unchanged)
// ===========================================================================

__global__ __launch_bounds__(256) void cvt_bf16_kernel(const float* __restrict__ src,
                                                       ushort_t* __restrict__ dst, int n8) {
    int i = blockIdx.x * 256 + threadIdx.x;
    if (i < n8) {
        const float4* s4 = (const float4*)src;
        float4 a = s4[2 * i], b = s4[2 * i + 1];
        uint4 o;
        o.x = f2bf_pack2(a.x, a.y);
        o.y = f2bf_pack2(a.z, a.w);
        o.z = f2bf_pack2(b.x, b.y);
        o.w = f2bf_pack2(b.z, b.w);
        ((uint4*)dst)[i] = o;
    }
}

__global__ __launch_bounds__(256) void init_hu(const float* __restrict__ h_f,
                                               const float* __restrict__ h_b,
                                               float* __restrict__ H,
                                               ushort_t* __restrict__ Ubf) {
    int i = blockIdx.x * 256 + threadIdx.x;
    float a = h_f[i], b = h_b[i];
    H[i]       = a;  H[NH + i]   = b;
    Ubf[i]     = bf16_1(a);
    Ubf[NH + i] = bf16_1(b);
}

__global__ __launch_bounds__(512, 4) void ode_mv1(
    const ushort_t* __restrict__ W1b, const float* __restrict__ b1,
    const ushort_t* __restrict__ Ubf, ushort_t* __restrict__ Vbf)
{
    __shared__ uint4 uS[1024];
    const int t = threadIdx.x;
    {
        const uint4* U4 = (const uint4*)Ubf;
        uS[t]       = U4[t];
        uS[t + 512] = U4[t + 512];
    }
    __syncthreads();

    const int l   = t & 63;
    const int row = blockIdx.x * 8 + (t >> 6);
    const uint4* __restrict__ W4 = (const uint4*)(W1b + (size_t)row * NH);

    float s0 = 0.f, s1 = 0.f;
#pragma unroll
    for (int i = 0; i < 8; ++i) {
        int idx = l + 64 * i;
        uint4 wv = W4[idx];
        uint4 u0 = uS[idx];
        uint4 u1 = uS[512 + idx];
        float wf[8], a0[8], a1[8];
        bf16x8_to_f32(wv, wf);
        bf16x8_to_f32(u0, a0);
        bf16x8_to_f32(u1, a1);
#pragma unroll
        for (int k = 0; k < 8; ++k) {
            s0 += wf[k] * a0[k];
            s1 += wf[k] * a1[k];
        }
    }
    s0 = wave_reduce64(s0);
    s1 = wave_reduce64(s1);
    if (l == 0) {
        float bb = b1[row];
        Vbf[row]      = bf16_1(tanhf(s0 + bb));
        Vbf[NH + row] = bf16_1(tanhf(s1 + bb));
    }
}

__global__ __launch_bounds__(512, 4) void ode_mv2(
    const ushort_t* __restrict__ W2b, const float* __restrict__ b2,
    const ushort_t* __restrict__ Vbf,
    const float* __restrict__ tf, const float* __restrict__ tb, int sidx,
    float wgt, float cnext, int stage,
    float* __restrict__ H, float* __restrict__ ACC,
    ushort_t* __restrict__ Ubf)
{
    __shared__ uint4 vS[1024];
    const int t = threadIdx.x;
    {
        const uint4* V4 = (const uint4*)Vbf;
        vS[t]       = V4[t];
        vS[t + 512] = V4[t + 512];
    }
    __syncthreads();

    const int l   = t & 63;
    const int row = blockIdx.x * 8 + (t >> 6);
    const uint4* __restrict__ W4 = (const uint4*)(W2b + (size_t)row * NH);
    const float dt0 = tf[sidx + 1] - tf[sidx];
    const float dt1 = tb[sidx + 1] - tb[sidx];

    float s0 = 0.f, s1 = 0.f;
#pragma unroll
    for (int i = 0; i < 8; ++i) {
        int idx = l + 64 * i;
        uint4 wv = W4[idx];
        uint4 v0 = vS[idx];
        uint4 v1 = vS[512 + idx];
        float wf[8], a0[8], a1[8];
        bf16x8_to_f32(wv, wf);
        bf16x8_to_f32(v0, a0);
        bf16x8_to_f32(v1, a1);
#pragma unroll
        for (int k = 0; k < 8; ++k) {
            s0 += wf[k] * a0[k];
            s1 += wf[k] * a1[k];
        }
    }
    s0 = wave_reduce64(s0);
    s1 = wave_reduce64(s1);
    if (l == 0) {
        float bb = b2[row];
        float k0 = s0 + bb, k1 = s1 + bb;
        float base0 = (stage == 0) ? H[row]      : ACC[row];
        float base1 = (stage == 0) ? H[NH + row] : ACC[NH + row];
        float a0 = base0 + wgt * (dt0 / 6.f) * k0;
        float a1 = base1 + wgt * (dt1 / 6.f) * k1;
        ACC[row]      = a0;
        ACC[NH + row] = a1;
        if (stage == 3) {
            H[row]      = a0;
            H[NH + row] = a1;
            Ubf[row]      = bf16_1(a0);
            Ubf[NH + row] = bf16_1(a1);
        } else {
            Ubf[row]      = bf16_1(H[row]      + cnext * dt0 * k0);
            Ubf[NH + row] = bf16_1(H[NH + row] + cnext * dt1 * k1);
        }
    }
}

__global__ __launch_bounds__(256) void init_h_kernel(const float* __restrict__ h_f,
                                                     const float* __restrict__ h_b,
                                                     float* __restrict__ H) {
    int i = blockIdx.x * 256 + threadIdx.x;
    H[i]      = h_f[i];
    H[NH + i] = h_b[i];
}

__global__ __launch_bounds__(256) void rk4_mv1_f32(
    const float* __restrict__ W1, const float* __restrict__ b1,
    const float* __restrict__ H,  const float* __restrict__ Kv,
    const float* __restrict__ tf, const float* __restrict__ tb,
    int tidx, float coef, int useK,
    float* __restrict__ V)
{
    const int row  = blockIdx.x * 4 + (threadIdx.x >> 6);
    const int lane = threadIdx.x & 63;
    const float a0 = coef * (tf[tidx + 1] - tf[tidx]);
    const float a1 = coef * (tb[tidx + 1] - tb[tidx]);

    const float4* __restrict__ W4 = (const float4*)(W1 + (size_t)row * NH);
    const float4* __restrict__ x0 = (const float4*)(H);
    const float4* __restrict__ x1 = (const float4*)(H + NH);
    const float4* __restrict__ k0 = (const float4*)(Kv);
    const float4* __restrict__ k1 = (const float4*)(Kv + NH);

    float s0 = 0.f, s1 = 0.f;
    if (useK) {
#pragma unroll 8
        for (int i = 0; i < NH / 4 / 64; ++i) {
            int idx = lane + i * 64;
            float4 w  = W4[idx];
            float4 h0 = x0[idx], h1 = x1[idx];
            float4 p0 = k0[idx], p1 = k1[idx];
            s0 += w.x * (h0.x + a0 * p0.x) + w.y * (h0.y + a0 * p0.y)
                + w.z * (h0.z + a0 * p0.z) + w.w * (h0.w + a0 * p0.w);
            s1 += w.x * (h1.x + a1 * p1.x) + w.y * (h1.y + a1 * p1.y)
                + w.z * (h1.z + a1 * p1.z) + w.w * (h1.w + a1 * p1.w);
        }
    } else {
#pragma unroll 8
        for (int i = 0; i < NH / 4 / 64; ++i) {
            int idx = lane + i * 64;
            float4 w  = W4[idx];
            float4 h0 = x0[idx], h1 = x1[idx];
            s0 += w.x * h0.x + w.y * h0.y + w.z * h0.z + w.w * h0.w;
            s1 += w.x * h1.x + w.y * h1.y + w.z * h1.z + w.w * h1.w;
        }
    }
    s0 = wave_reduce64(s0);
    s1 = wave_reduce64(s1);
    if (lane == 0) {
        float bb = b1[row];
        V[row]      = tanhf(s0 + bb);
        V[NH + row] = tanhf(s1 + bb);
    }
}

__global__ __launch_bounds__(256) void rk4_mv2_f32(
    const float* __restrict__ W2, const float* __restrict__ b2,
    const float* __restrict__ V,
    const float* __restrict__ tf, const float* __restrict__ tb,
    int tidx, float wgt,
    const float* __restrict__ Hbase,
    float* __restrict__ Kout, float* __restrict__ ACC)
{
    const int row  = blockIdx.x * 4 + (threadIdx.x >> 6);
    const int lane = threadIdx.x & 63;

    const float4* __restrict__ W4 = (const float4*)(W2 + (size_t)row * NH);
    const float4* __restrict__ v0 = (const float4*)(V);
    const float4* __restrict__ v1 = (const float4*)(V + NH);

    float s0 = 0.f, s1 = 0.f;
#pragma unroll 8
    for (int i = 0; i < NH / 4 / 64; ++i) {
        int idx = lane + i * 64;
        float4 w = W4[idx];
        float4 a = v0[idx], b = v1[idx];
        s0 += w.x * a.x + w.y * a.y + w.z * a.z + w.w * a.w;
        s1 += w.x * b.x + w.y * b.y + w.z * b.z + w.w * b.w;
    }
    s0 = wave_reduce64(s0);
    s1 = wave_reduce64(s1);
    if (lane == 0) {
        float bb  = b2[row];
        float k0v = s0 + bb;
        float k1v = s1 + bb;
        Kout[row]      = k0v;
        Kout[NH + row] = k1v;
        const float dt0 = tf[tidx + 1] - tf[tidx];
        const float dt1 = tb[tidx + 1] - tb[tidx];
        ACC[row]      = Hbase[row]      + wgt * (dt0 / 6.f) * k0v;
        ACC[NH + row] = Hbase[NH + row] + wgt * (dt1 / 6.f) * k1v;
    }
}

// ---------------------------------------------------------------------------
// GRU / head kernels (fp32 weights; used 1-2x each)
// ---------------------------------------------------------------------------
__global__ __launch_bounds__(256) void build_xcat_kernel(
    const float* __restrict__ x_f, const float* __restrict__ x_b,
    const float* __restrict__ H,
    float* __restrict__ xcat1, float* __restrict__ xcat2)
{
    int i = blockIdx.x * 256 + threadIdx.x;
    float xf = x_f[i], xb = x_b[i];
    xcat1[i]               = xf;
    xcat2[i]               = xf;
    xcat1[KCAT + i]        = xb;
    xcat2[KCAT + i]        = xb;
    xcat1[NH + i]          = H[i];
    xcat1[KCAT + NH + i]   = H[NH + i];
}

__global__ __launch_bounds__(256) void gru_mv1(
    const float* __restrict__ Wi, const float* __restrict__ bi,
    const float* __restrict__ xcat1, const float* __restrict__ H,
    float* __restrict__ G, float* __restrict__ xcat2)
{
    const int row  = blockIdx.x * 4 + (threadIdx.x >> 6);
    const int lane = threadIdx.x & 63;

    const float4* __restrict__ W4 = (const float4*)(Wi + (size_t)row * KCAT);
    const float4* __restrict__ c0 = (const float4*)(xcat1);
    const float4* __restrict__ c1 = (const float4*)(xcat1 + KCAT);

    float s0 = 0.f, s1 = 0.f;
#pragma unroll 8
    for (int i = 0; i < KCAT / 4 / 64; ++i) {
        int idx = lane + i * 64;
        float4 w = W4[idx];
        float4 a = c0[idx], b = c1[idx];
        s0 += w.x * a.x + w.y * a.y + w.z * a.z + w.w * a.w;
        s1 += w.x * b.x + w.y * b.y + w.z * b.z + w.w * b.w;
    }
    s0 = wave_reduce64(s0);
    s1 = wave_reduce64(s1);
    if (lane == 0) {
        float bb = bi[row];
        float g0 = 1.f / (1.f + expf(-(s0 + bb)));
        float g1 = 1.f / (1.f + expf(-(s1 + bb)));
        G[row]      = g0;
        G[NH + row] = g1;
        xcat2[NH + row]        = g0 * H[row];
        xcat2[KCAT + NH + row] = g1 * H[NH + row];
    }
}

__global__ __launch_bounds__(256) void gru_mv2(
    const float* __restrict__ Wi, const float* __restrict__ bi,
    const float* __restrict__ xcat2, const float* __restrict__ H,
    const float* __restrict__ G,
    float* __restrict__ out, float* __restrict__ hcat)
{
    const int row  = blockIdx.x * 4 + (threadIdx.x >> 6);
    const int lane = threadIdx.x & 63;

    const float4* __restrict__ W4 = (const float4*)(Wi + (size_t)row * KCAT);
    const float4* __restrict__ c0 = (const float4*)(xcat2);
    const float4* __restrict__ c1 = (const float4*)(xcat2 + KCAT);

    float s0 = 0.f, s1 = 0.f;
#pragma unroll 8
    for (int i = 0; i < KCAT / 4 / 64; ++i) {
        int idx = lane + i * 64;
        float4 w = W4[idx];
        float4 a = c0[idx], b = c1[idx];
        s0 += w.x * a.x + w.y * a.y + w.z * a.z + w.w * a.w;
        s1 += w.x * b.x + w.y * b.y + w.z * b.z + w.w * b.w;
    }
    s0 = wave_reduce64(s0);
    s1 = wave_reduce64(s1);
    if (lane == 0) {
        float bb  = bi[row];
        float hh0 = tanhf(s0 + bb);
        float hh1 = tanhf(s1 + bb);
        float g0  = G[row], g1 = G[NH + row];
        float hf  = g0 * H[row]      + (1.f - g0) * hh0;
        float hb  = g1 * H[NH + row] + (1.f - g1) * hh1;
        out[NH + row]     = hf;
        out[2 * NH + row] = hb;
        hcat[row]      = hf;
        hcat[NH + row] = hb;
    }
}

__global__ __launch_bounds__(256) void h2o_mv(
    const float* __restrict__ W, const float* __restrict__ b,
    const float* __restrict__ hcat, float* __restrict__ out)
{
    const int row  = blockIdx.x * 4 + (threadIdx.x >> 6);
    const int lane = threadIdx.x & 63;

    const float4* __restrict__ W4 = (const float4*)(W + (size_t)row * KCAT);
    const float4* __restrict__ x4 = (const float4*)(hcat);

    float s = 0.f;
#pragma unroll 8
    for (int i = 0; i < KCAT / 4 / 64; ++i) {
        int idx = lane + i * 64;
        float4 w = W4[idx];
        float4 a = x4[idx];
        s += w.x * a.x + w.y * a.y + w.z * a.z + w.w * a.w;
    }
    s = wave_reduce64(s);
    if (lane == 0)
        out[row] = s + b[row];
}

// ---------------------------------------------------------------------------
extern "C" void kernel_launch(void* const* d_in, const int* in_sizes, int n_in,
                              void* d_out, int out_size, void* d_ws, size_t ws_size,
                              hipStream_t stream) {
    const float* x_f   = (const float*)d_in[0];
    const float* x_b   = (const float*)d_in[1];
    const float* h_f   = (const float*)d_in[2];
    const float* h_b   = (const float*)d_in[3];
    const float* t_f   = (const float*)d_in[4];
    const float* t_b   = (const float*)d_in[5];
    const float* i2h_W = (const float*)d_in[6];
    const float* i2h_b = (const float*)d_in[7];
    const float* h2o_W = (const float*)d_in[8];
    const float* h2o_b = (const float*)d_in[9];
    const float* f_W1  = (const float*)d_in[10];
    const float* f_b1  = (const float*)d_in[11];
    const float* f_W2  = (const float*)d_in[12];
    const float* f_b2  = (const float*)d_in[13];
    float* out = (float*)d_out;

    // ---- workspace layout (all offsets 16B-aligned) ----
    float* ws    = (float*)d_ws;
    float* Hg    = ws;                  // 2*NH fp32
    float* ACCg  = Hg    + 2 * NH;      // 2*NH fp32
    float* Vg32  = ACCg  + 2 * NH;      // 2*NH fp32 (fallback V)
    float* Kg32  = Vg32  + 2 * NH;      // 2*NH fp32 (fallback K)
    float* xcat1 = Kg32  + 2 * NH;      // 2*KCAT
    float* xcat2 = xcat1 + 2 * KCAT;    // 2*KCAT
    float* G     = xcat2 + 2 * KCAT;    // 2*NH
    float* hcat  = G     + 2 * NH;      // KCAT
    float* fend  = hcat  + KCAT;
    ushort_t* Ubf = (ushort_t*)fend;            // 2*NH bf16 (16 KB)
    ushort_t* Vbf = Ubf + 2 * NH;               // 2*NH bf16 (16 KB)
    ushort_t* W1b = Vbf + 2 * NH;               // NH*NH bf16 (32 MB, fallback only)
    ushort_t* W2b = W1b + (size_t)NH * NH;      // NH*NH bf16 (32 MB, fallback only)
    size_t need = (size_t)((char*)(W2b + (size_t)NH * NH) - (char*)d_ws);
    const bool fast = ws_size >= need;

    // coop-path buffers alias the (unused-in-coop) W1b region
    unsigned* Ugu  = (unsigned*)W1b;               // NH uints (16 KB)
    unsigned* Vgu  = Ugu + NH;                     // NH uints (16 KB)
    unsigned* barp = Vgu + NH;                     // 1024 uints (4 KB)
    size_t coop_need = (size_t)((char*)(barp + 1024) - (char*)d_ws);

    dim3 blk(256);

    bool ode_done = false;
    if (ws_size >= coop_need) {
        zero_bar<<<1, 64, 0, stream>>>(barp);
        void* kargs[] = { (void*)&f_W1, (void*)&f_b1, (void*)&f_W2, (void*)&f_b2,
                          (void*)&h_f,  (void*)&h_b,  (void*)&t_f,  (void*)&t_b,
                          (void*)&Ugu,  (void*)&Vgu,  (void*)&barp, (void*)&Hg };
        hipError_t e = hipLaunchCooperativeKernel(ode_persistent, dim3(NBLK), dim3(1024),
                                                  kargs, 0, stream);
        ode_done = (e == hipSuccess);
    }

    if (!ode_done) {
        if (fast) {
            const int n8 = NH * NH / 8;
            cvt_bf16_kernel<<<n8 / 256, blk, 0, stream>>>(f_W1, W1b, n8);
            cvt_bf16_kernel<<<n8 / 256, blk, 0, stream>>>(f_W2, W2b, n8);
            init_hu<<<NH / 256, blk, 0, stream>>>(h_f, h_b, Hg, Ubf);

            for (int s = 0; s < TPTS - 1; ++s) {
                ode_mv1<<<512, 512, 0, stream>>>(W1b, f_b1, Ubf, Vbf);
                ode_mv2<<<512, 512, 0, stream>>>(W2b, f_b2, Vbf, t_f, t_b, s,
                                                 1.f, 0.5f, 0, Hg, ACCg, Ubf);
                ode_mv1<<<512, 512, 0, stream>>>(W1b, f_b1, Ubf, Vbf);
                ode_mv2<<<512, 512, 0, stream>>>(W2b, f_b2, Vbf, t_f, t_b, s,
                                                 2.f, 0.5f, 1, Hg, ACCg, Ubf);
                ode_mv1<<<512, 512, 0, stream>>>(W1b, f_b1, Ubf, Vbf);
                ode_mv2<<<512, 512, 0, stream>>>(W2b, f_b2, Vbf, t_f, t_b, s,
                                                 2.f, 1.0f, 2, Hg, ACCg, Ubf);
                ode_mv1<<<512, 512, 0, stream>>>(W1b, f_b1, Ubf, Vbf);
                ode_mv2<<<512, 512, 0, stream>>>(W2b, f_b2, Vbf, t_f, t_b, s,
                                                 1.f, 0.0f, 3, Hg, ACCg, Ubf);
            }
        } else {
            const int mv_grid = NH / 4;
            init_h_kernel<<<NH / 256, blk, 0, stream>>>(h_f, h_b, Hg);
            float* H   = Hg;
            float* ACC = ACCg;
            for (int s = 0; s < TPTS - 1; ++s) {
                rk4_mv1_f32<<<mv_grid, blk, 0, stream>>>(f_W1, f_b1, H, Kg32, t_f, t_b, s, 0.0f, 0, Vg32);
                rk4_mv2_f32<<<mv_grid, blk, 0, stream>>>(f_W2, f_b2, Vg32, t_f, t_b, s, 1.0f, H,   Kg32, ACC);
                rk4_mv1_f32<<<mv_grid, blk, 0, stream>>>(f_W1, f_b1, H, Kg32, t_f, t_b, s, 0.5f, 1, Vg32);
                rk4_mv2_f32<<<mv_grid, blk, 0, stream>>>(f_W2, f_b2, Vg32, t_f, t_b, s, 2.0f, ACC, Kg32, ACC);
                rk4_mv1_f32<<<mv_grid, blk, 0, stream>>>(f_W1, f_b1, H, Kg32, t_f, t_b, s, 0.5f, 1, Vg32);
                rk4_mv2_f32<<<mv_grid, blk, 0, stream>>>(f_W2, f_b2, Vg32, t_f, t_b, s, 2.0f, ACC, Kg32, ACC);
                rk4_mv1_f32<<<mv_grid, blk, 0, stream>>>(f_W1, f_b1, H, Kg32, t_f, t_b, s, 1.0f, 1, Vg32);
                rk4_mv2_f32<<<mv_grid, blk, 0, stream>>>(f_W2, f_b2, Vg32, t_f, t_b, s, 1.0f, ACC, Kg32, ACC);
                float* tmp = H; H = ACC; ACC = tmp;
            }
            if (H != Hg) {
                hipMemcpyAsync(Hg, H, 2 * NH * sizeof(float), hipMemcpyDeviceToDevice, stream);
            }
        }
    }

    const int mv_grid = NH / 4;
    build_xcat_kernel<<<NH / 256, blk, 0, stream>>>(x_f, x_b, Hg, xcat1, xcat2);
    gru_mv1<<<mv_grid, blk, 0, stream>>>(i2h_W, i2h_b, xcat1, Hg, G, xcat2);
    gru_mv2<<<mv_grid, blk, 0, stream>>>(i2h_W, i2h_b, xcat2, Hg, G, out, hcat);
    h2o_mv <<<mv_grid, blk, 0, stream>>>(h2o_W, h2o_b, hcat, out);
}